// Round 9
// baseline (46.336 us; speedup 1.0000x reference)
//
#include <hip/hip_runtime.h>
#include <stdint.h>

typedef unsigned long long u64;
typedef __attribute__((ext_vector_type(4))) float f32x4;    // MFMA acc / f32 LDS read

#define IN_FEATURES 256
#define UNITS 256
#define TM 16                 // rows per tile
#define TILES 4               // tiles per block -> 64 rows/block
#define ROW_BYTES 1024        // 256 f32

// ---- sign helpers ----
// fp8 e4m3fn: +1.0 = 0x38, -1.0 = 0xB8, 0 = 0x00. Exact for {-1,0,1}.
__device__ __forceinline__ uint sgn_fp8(float f) {
    uint u = __float_as_uint(f);
    return ((u << 1) == 0u) ? 0u : (0x38u | ((u >> 24) & 0x80u));
}
__device__ __forceinline__ u64 pack8_fp8(f32x4 lo, f32x4 hi) {
    uint p0 = sgn_fp8(lo[0]) | (sgn_fp8(lo[1]) << 8) | (sgn_fp8(lo[2]) << 16) | (sgn_fp8(lo[3]) << 24);
    uint p1 = sgn_fp8(hi[0]) | (sgn_fp8(hi[1]) << 8) | (sgn_fp8(hi[2]) << 16) | (sgn_fp8(hi[3]) << 24);
    return (u64)p0 | ((u64)p1 << 32);
}

// ---------------------------------------------------------------------------
// Pack kernel (verified R7/R8): w -> sign-fp8 in MFMA B-fragment layout.
// Fragment (ks, ct, lane): col = ct*16 + (lane&15), k = ks*32 + (lane>>4)*8 .. +8
// fragB[(ks*16+ct)*64 + lane] = 8 fp8 bytes, k-ascending.  Total 64 KB.
// ---------------------------------------------------------------------------
__global__ __launch_bounds__(256) void pack_w_frag8(const float* __restrict__ w,
                                                    u64* __restrict__ fragB) {
    __shared__ uchar ls[256][20];   // [k][c], padded
    const int ct = blockIdx.x;
    const int t = threadIdx.x;

    const float4* wr = (const float4*)(w + (size_t)t * UNITS + ct * 16);
#pragma unroll
    for (int i = 0; i < 4; ++i) {
        const float4 v = wr[i];
        ls[t][i * 4 + 0] = (uchar)sgn_fp8(v.x);
        ls[t][i * 4 + 1] = (uchar)sgn_fp8(v.y);
        ls[t][i * 4 + 2] = (uchar)sgn_fp8(v.z);
        ls[t][i * 4 + 3] = (uchar)sgn_fp8(v.w);
    }
    __syncthreads();

#pragma unroll
    for (int h = 0; h < 2; ++h) {
        const int f = t + h * 256;
        const int ks = f >> 6;
        const int lane = f & 63;
        const int c = lane & 15;
        const int k0 = ks * 32 + (lane >> 4) * 8;
        u64 val = 0;
#pragma unroll
        for (int j = 0; j < 8; ++j) val |= ((u64)ls[k0 + j][c]) << (8 * j);
        fragB[(size_t)(ks * 16 + ct) * 64 + lane] = val;
    }
}

// ---------------------------------------------------------------------------
// Async DMA of one 16-row f32 tile into LDS (4 instr/wave, one row per instr:
// 64 lanes x 16B = 1024B = full row). Linear LDS dest; the 16B-chunk swizzle
// (slot = chunk ^ (row&7)) is applied on the GLOBAL source (rule #21
// involution; verified absmax-0 in R8). Zero VGPRs held -> cannot be sunk.
// ---------------------------------------------------------------------------
__device__ __forceinline__ void dma_tile(const char* __restrict__ xrow0,
                                         float (*buf)[256], int lane, int wid) {
#pragma unroll
    for (int i = 0; i < 4; ++i) {
        const int row = wid * 4 + i;
        const int m = row & 7;
        const char* src = xrow0 + (size_t)row * ROW_BYTES + ((lane ^ m) << 4);
        __builtin_amdgcn_global_load_lds(
            (const __attribute__((address_space(1))) void*)(uintptr_t)src,
            (__attribute__((address_space(3))) void*)(uint32_t)(uintptr_t)&buf[row][0],
            16, 0, 0);
    }
}

// ---------------------------------------------------------------------------
// Compute one 16-row tile (swizzled LDS reads + in-reg sign->fp8, fp8 MFMA,
// swapped operands -> transposed C). Store is done by the caller AFTER the
// WAR barrier so the DMA of tile t+2 issues before the stores (vmcnt calc).
// ---------------------------------------------------------------------------
__device__ __forceinline__ void compute_tile16(const float (*buf)[256],
                                               const u64 (&breg)[8][4],
                                               f32x4 (&acc)[4], int lane) {
    const int rl = lane & 15;
    const int m = rl & 7;
    const int c2 = (lane >> 4) * 2;

#pragma unroll
    for (int nt = 0; nt < 4; ++nt) acc[nt] = (f32x4){0.f, 0.f, 0.f, 0.f};

#pragma unroll
    for (int ks = 0; ks < 8; ++ks) {
        const int c0 = ks * 8 + c2;
        const f32x4 lo = *(const f32x4*)&buf[rl][(c0 ^ m) << 2];
        const f32x4 hi = *(const f32x4*)&buf[rl][((c0 + 1) ^ m) << 2];
        const long a = (long)pack8_fp8(lo, hi);
#pragma unroll
        for (int nt = 0; nt < 4; ++nt)
            acc[nt] = __builtin_amdgcn_mfma_f32_16x16x32_fp8_fp8(
                (long)breg[ks][nt], a, acc[nt], 0, 0, 0);
    }
}

// ---------------------------------------------------------------------------
// Main kernel: ring-2 of 16KB tiles, 4 blocks/CU, exact issue-counted vmcnt.
// Issue order: breg(32), DMA0(4), DMA1(4) | t0: w(4) bar comp bar DMA2 st0 |
// t1: w(8) bar comp bar DMA3 st1 | t2: w(12) bar comp bar st2 | t3: w(8) ...
// (vmcnt decrements in program order, so counts are exact regardless of
// store-retirement timing.)
// ---------------------------------------------------------------------------
__global__ __launch_bounds__(256, 4) void bdense_pipe(const float* __restrict__ x,
                                                      const u64* __restrict__ fragB,
                                                      float* __restrict__ out) {
    __shared__ float ring[2][TM][256];   // 32 KB -> 4+ blocks/CU

    const int tid = threadIdx.x;
    const int lane = tid & 63;
    const int wid = tid >> 6;
    const long row0 = (long)blockIdx.x * (TM * TILES);
    const int ct0 = wid * 4;

    // B fragments in registers for the whole kernel (32 u64 = 64 VGPRs).
    u64 breg[8][4];
#pragma unroll
    for (int ks = 0; ks < 8; ++ks)
#pragma unroll
        for (int nt = 0; nt < 4; ++nt)
            breg[ks][nt] = fragB[(size_t)(ks * 16 + ct0 + nt) * 64 + lane];

    const char* xb = (const char*)(x + (size_t)row0 * IN_FEATURES);

    dma_tile(xb, ring[0], lane, wid);                       // DMA tile 0
    dma_tile(xb + (size_t)TM * ROW_BYTES, ring[1], lane, wid);  // DMA tile 1

    const int cl4 = (lane >> 4) * 4;
    const int colbase = wid * 64;
    const int rl = lane & 15;

#pragma unroll
    for (int t = 0; t < TILES; ++t) {
        // exact counted wait: retire everything through DMA(t)
        if (t == 0)      asm volatile("s_waitcnt vmcnt(4)" ::: "memory");
        else if (t == 1) asm volatile("s_waitcnt vmcnt(8)" ::: "memory");
        else if (t == 2) asm volatile("s_waitcnt vmcnt(12)" ::: "memory");
        else             asm volatile("s_waitcnt vmcnt(8)" ::: "memory");
        __builtin_amdgcn_sched_barrier(0);
        __builtin_amdgcn_s_barrier();        // tile t visible to all waves

        f32x4 acc[4];
        compute_tile16(ring[t & 1], breg, acc, lane);

        __builtin_amdgcn_s_barrier();        // all waves done reading ring[t&1]

        if (t + 2 < TILES)                    // refill the buffer just freed
            dma_tile(xb + (size_t)(t + 2) * TM * ROW_BYTES, ring[t & 1], lane, wid);

        // store tile t (transposed-C: lane holds row rl, 4 consecutive cols)
        const long rowt = row0 + (long)t * TM + rl;
#pragma unroll
        for (int nt = 0; nt < 4; ++nt)
            *(f32x4*)(out + rowt * UNITS + colbase + nt * 16 + cl4) = acc[nt];
    }
}

// ---------------------------------------------------------------------------
// Fallback (ws too small): round-2 popcount path, known-correct.
// ---------------------------------------------------------------------------
__global__ __launch_bounds__(256) void pack_w_bits(const float* __restrict__ w,
                                                   u64* __restrict__ wp) {
    const int t = blockIdx.x;
    const int j = threadIdx.x;
    u64 s = 0, z = 0;
#pragma unroll
    for (int b = 0; b < 64; ++b) {
        const float v = w[(4 * b + t) * UNITS + j];
        s |= ((u64)(v < 0.0f)) << b;
        z |= ((u64)(v != 0.0f)) << b;
    }
    wp[j * 4 + t] = s;
    wp[1024 + j * 4 + t] = z;
}

__global__ __launch_bounds__(256) void bdense_pop(const float4* __restrict__ x4,
                                                  const u64* __restrict__ wp,
                                                  float4* __restrict__ out4) {
    const int tid = threadIdx.x;
    const int lane = tid & 63;
    const int wid = tid >> 6;
    const long row0 = (long)blockIdx.x * 32 + (long)wid * 8;

    u64 ws_[4][4], wz_[4][4];
#pragma unroll
    for (int i = 0; i < 4; ++i)
#pragma unroll
        for (int t = 0; t < 4; ++t) {
            ws_[i][t] = wp[(4 * lane + i) * 4 + t];
            wz_[i][t] = wp[1024 + (4 * lane + i) * 4 + t];
        }

#pragma unroll
    for (int r = 0; r < 8; ++r) {
        const float4 v = x4[(row0 + r) * (IN_FEATURES / 4) + lane];
        u64 rs[4], rz[4];
        rs[0] = __ballot(v.x < 0.0f); rz[0] = __ballot(v.x != 0.0f);
        rs[1] = __ballot(v.y < 0.0f); rz[1] = __ballot(v.y != 0.0f);
        rs[2] = __ballot(v.z < 0.0f); rz[2] = __ballot(v.z != 0.0f);
        rs[3] = __ballot(v.w < 0.0f); rz[3] = __ballot(v.w != 0.0f);
        float o[4];
#pragma unroll
        for (int i = 0; i < 4; ++i) {
            int nzc = 0, ngc = 0;
#pragma unroll
            for (int t = 0; t < 4; ++t) {
                const u64 nz = rz[t] & wz_[i][t];
                const u64 d = (rs[t] ^ ws_[i][t]) & nz;
                nzc += __popcll(nz);
                ngc += __popcll(d);
            }
            o[i] = (float)(nzc - 2 * ngc);
        }
        out4[(row0 + r) * (UNITS / 4) + lane] = make_float4(o[0], o[1], o[2], o[3]);
    }
}

extern "C" void kernel_launch(void* const* d_in, const int* in_sizes, int n_in,
                              void* d_out, int out_size, void* d_ws, size_t ws_size,
                              hipStream_t stream) {
    const float* x = (const float*)d_in[0];
    const float* w = (const float*)d_in[1];
    float* out = (float*)d_out;

    const int batch = in_sizes[0] / IN_FEATURES;  // 65536

    if (ws_size >= 65536 && batch % (TM * TILES) == 0) {
        u64* fragB = (u64*)d_ws;
        pack_w_frag8<<<16, 256, 0, stream>>>(w, fragB);
        bdense_pipe<<<batch / (TM * TILES), 256, 0, stream>>>(x, fragB, out);
    } else {
        u64* wp = (u64*)d_ws;  // 16 KB
        pack_w_bits<<<4, 256, 0, stream>>>(w, wp);
        bdense_pop<<<batch / 32, 256, 0, stream>>>((const float4*)x, wp, (float4*)out);
    }
}

// Round 10
// 35.553 us; speedup vs baseline: 1.3033x; 1.3033x over previous
//
#include <hip/hip_runtime.h>
#include <stdint.h>

typedef unsigned long long u64;
typedef __attribute__((ext_vector_type(4))) float f32x4;    // MFMA acc / f32 LDS read

#define IN_FEATURES 256
#define UNITS 256
#define BM 32                 // rows per block
#define ROW_BYTES 1024        // 256 f32

// ---- sign helpers ----
// fp8 e4m3fn: +1.0 = 0x38, -1.0 = 0xB8, 0 = 0x00. Exact for {-1,0,1}.
__device__ __forceinline__ uint sgn_fp8(float f) {
    uint u = __float_as_uint(f);
    return ((u << 1) == 0u) ? 0u : (0x38u | ((u >> 24) & 0x80u));
}
__device__ __forceinline__ u64 pack8_fp8(f32x4 lo, f32x4 hi) {
    uint p0 = sgn_fp8(lo[0]) | (sgn_fp8(lo[1]) << 8) | (sgn_fp8(lo[2]) << 16) | (sgn_fp8(lo[3]) << 24);
    uint p1 = sgn_fp8(hi[0]) | (sgn_fp8(hi[1]) << 8) | (sgn_fp8(hi[2]) << 16) | (sgn_fp8(hi[3]) << 24);
    return (u64)p0 | ((u64)p1 << 32);
}

// ---------------------------------------------------------------------------
// Pack kernel (verified R7-R9): w -> sign-fp8 in MFMA B-fragment layout.
// Fragment (ks, ct, lane): col = ct*16 + (lane&15), k = ks*32 + (lane>>4)*8 .. +8
// fragB[(ks*16+ct)*64 + lane] = 8 fp8 bytes, k-ascending.  Total 64 KB.
// ---------------------------------------------------------------------------
__global__ __launch_bounds__(256) void pack_w_frag8(const float* __restrict__ w,
                                                    u64* __restrict__ fragB) {
    __shared__ unsigned char ls[256][20];   // [k][c], padded
    const int ct = blockIdx.x;
    const int t = threadIdx.x;

    const float4* wr = (const float4*)(w + (size_t)t * UNITS + ct * 16);
#pragma unroll
    for (int i = 0; i < 4; ++i) {
        const float4 v = wr[i];
        ls[t][i * 4 + 0] = (unsigned char)sgn_fp8(v.x);
        ls[t][i * 4 + 1] = (unsigned char)sgn_fp8(v.y);
        ls[t][i * 4 + 2] = (unsigned char)sgn_fp8(v.z);
        ls[t][i * 4 + 3] = (unsigned char)sgn_fp8(v.w);
    }
    __syncthreads();

#pragma unroll
    for (int h = 0; h < 2; ++h) {
        const int f = t + h * 256;
        const int ks = f >> 6;
        const int lane = f & 63;
        const int c = lane & 15;
        const int k0 = ks * 32 + (lane >> 4) * 8;
        u64 val = 0;
#pragma unroll
        for (int j = 0; j < 8; ++j) val |= ((u64)ls[k0 + j][c]) << (8 * j);
        fragB[(size_t)(ks * 16 + ct) * 64 + lane] = val;
    }
}

// ---------------------------------------------------------------------------
// Main kernel (R5 structure + zero-VGPR DMA staging):
//   1. breg: B fragments into registers (32 u64, L2-resident, coalesced).
//   2. DMA 32 rows of RAW f32 x into LDS via global_load_lds (8 instr/wave,
//      zero VGPRs held -> all issue immediately; 32 KB/block in flight).
//      Linear LDS dest; 16B-chunk swizzle (chunk ^ (row&7)) applied on the
//      GLOBAL source (verified involution, R8/R9 absmax-0).
//   3. ONE vmcnt(0) + barrier.
//   4. Compute: swizzled f32x4 LDS reads + in-reg sign->fp8 + fp8 MFMA
//      (swapped operands, verified) ; f32x4 transposed-C stores (verified).
// Grid 2048 (= 2 generations at 4 blocks/CU): gen-2 reads overlap gen-1
// stores for device-level read/write stream overlap.
// ---------------------------------------------------------------------------
__global__ __launch_bounds__(256, 4) void bdense_v10(const float* __restrict__ x,
                                                     const u64* __restrict__ fragB,
                                                     float* __restrict__ out) {
    __shared__ float buf[BM][256];   // 32 KB, raw f32

    const int tid = threadIdx.x;
    const int lane = tid & 63;
    const int wid = tid >> 6;
    const long row0 = (long)blockIdx.x * BM;
    const int ct0 = wid * 4;

    // ---- 1. B fragments (32 x u64 = 64 VGPRs) ----
    u64 breg[8][4];
#pragma unroll
    for (int ks = 0; ks < 8; ++ks)
#pragma unroll
        for (int nt = 0; nt < 4; ++nt)
            breg[ks][nt] = fragB[(size_t)(ks * 16 + ct0 + nt) * 64 + lane];

    // ---- 2. DMA stage: wave wid stages rows wid*8 .. wid*8+7 (1 row/instr) ----
    const char* xb = (const char*)(x + (size_t)row0 * IN_FEATURES);
#pragma unroll
    for (int r = 0; r < 8; ++r) {
        const int row = wid * 8 + r;               // row & 7 == r
        const char* src = xb + (size_t)row * ROW_BYTES + ((lane ^ r) << 4);
        __builtin_amdgcn_global_load_lds(
            (const __attribute__((address_space(1))) void*)(uintptr_t)src,
            (__attribute__((address_space(3))) void*)(uint32_t)(uintptr_t)&buf[row][0],
            16, 0, 0);
    }
    __builtin_amdgcn_sched_barrier(0);

    // ---- 3. single drain + barrier ----
    asm volatile("s_waitcnt vmcnt(0)" ::: "memory");
    __builtin_amdgcn_sched_barrier(0);
    __builtin_amdgcn_s_barrier();

    // ---- 4. compute ----
    const int rl = lane & 15;
    const int m = rl & 7;                 // (mt*16+rl)&7 == rl&7
    const int c2 = (lane >> 4) * 2;

    f32x4 acc[2][4];
#pragma unroll
    for (int mt = 0; mt < 2; ++mt)
#pragma unroll
        for (int nt = 0; nt < 4; ++nt) acc[mt][nt] = (f32x4){0.f, 0.f, 0.f, 0.f};

#pragma unroll
    for (int ks = 0; ks < 8; ++ks) {
        const int c0 = ks * 8 + c2;       // 16B chunk index within row (even)
        u64 a[2];
#pragma unroll
        for (int mt = 0; mt < 2; ++mt) {
            const int row = mt * 16 + rl;
            const f32x4 lo = *(const f32x4*)&buf[row][(c0 ^ m) << 2];
            const f32x4 hi = *(const f32x4*)&buf[row][((c0 + 1) ^ m) << 2];
            a[mt] = pack8_fp8(lo, hi);
        }
#pragma unroll
        for (int nt = 0; nt < 4; ++nt) {
            acc[0][nt] = __builtin_amdgcn_mfma_f32_16x16x32_fp8_fp8(
                (long)breg[ks][nt], (long)a[0], acc[0][nt], 0, 0, 0);
            acc[1][nt] = __builtin_amdgcn_mfma_f32_16x16x32_fp8_fp8(
                (long)breg[ks][nt], (long)a[1], acc[1][nt], 0, 0, 0);
        }
    }

    // ---- stores: transposed-C, lane holds row rl, 4 consecutive cols ----
    const int cl4 = (lane >> 4) * 4;
    const int colbase = wid * 64;
#pragma unroll
    for (int mt = 0; mt < 2; ++mt) {
        const long rowt = row0 + mt * 16 + rl;
#pragma unroll
        for (int nt = 0; nt < 4; ++nt)
            *(f32x4*)(out + rowt * UNITS + colbase + nt * 16 + cl4) = acc[mt][nt];
    }
}

// ---------------------------------------------------------------------------
// Fallback (ws too small): round-2 popcount path, known-correct.
// ---------------------------------------------------------------------------
__global__ __launch_bounds__(256) void pack_w_bits(const float* __restrict__ w,
                                                   u64* __restrict__ wp) {
    const int t = blockIdx.x;
    const int j = threadIdx.x;
    u64 s = 0, z = 0;
#pragma unroll
    for (int b = 0; b < 64; ++b) {
        const float v = w[(4 * b + t) * UNITS + j];
        s |= ((u64)(v < 0.0f)) << b;
        z |= ((u64)(v != 0.0f)) << b;
    }
    wp[j * 4 + t] = s;
    wp[1024 + j * 4 + t] = z;
}

__global__ __launch_bounds__(256) void bdense_pop(const float4* __restrict__ x4,
                                                  const u64* __restrict__ wp,
                                                  float4* __restrict__ out4) {
    const int tid = threadIdx.x;
    const int lane = tid & 63;
    const int wid = tid >> 6;
    const long row0 = (long)blockIdx.x * 32 + (long)wid * 8;

    u64 ws_[4][4], wz_[4][4];
#pragma unroll
    for (int i = 0; i < 4; ++i)
#pragma unroll
        for (int t = 0; t < 4; ++t) {
            ws_[i][t] = wp[(4 * lane + i) * 4 + t];
            wz_[i][t] = wp[1024 + (4 * lane + i) * 4 + t];
        }

#pragma unroll
    for (int r = 0; r < 8; ++r) {
        const float4 v = x4[(row0 + r) * (IN_FEATURES / 4) + lane];
        u64 rs[4], rz[4];
        rs[0] = __ballot(v.x < 0.0f); rz[0] = __ballot(v.x != 0.0f);
        rs[1] = __ballot(v.y < 0.0f); rz[1] = __ballot(v.y != 0.0f);
        rs[2] = __ballot(v.z < 0.0f); rz[2] = __ballot(v.z != 0.0f);
        rs[3] = __ballot(v.w < 0.0f); rz[3] = __ballot(v.w != 0.0f);
        float o[4];
#pragma unroll
        for (int i = 0; i < 4; ++i) {
            int nzc = 0, ngc = 0;
#pragma unroll
            for (int t = 0; t < 4; ++t) {
                const u64 nz = rz[t] & wz_[i][t];
                const u64 d = (rs[t] ^ ws_[i][t]) & nz;
                nzc += __popcll(nz);
                ngc += __popcll(d);
            }
            o[i] = (float)(nzc - 2 * ngc);
        }
        out4[(row0 + r) * (UNITS / 4) + lane] = make_float4(o[0], o[1], o[2], o[3]);
    }
}

extern "C" void kernel_launch(void* const* d_in, const int* in_sizes, int n_in,
                              void* d_out, int out_size, void* d_ws, size_t ws_size,
                              hipStream_t stream) {
    const float* x = (const float*)d_in[0];
    const float* w = (const float*)d_in[1];
    float* out = (float*)d_out;

    const int batch = in_sizes[0] / IN_FEATURES;  // 65536

    if (ws_size >= 65536 && batch % BM == 0) {
        u64* fragB = (u64*)d_ws;
        pack_w_frag8<<<16, 256, 0, stream>>>(w, fragB);
        bdense_v10<<<batch / BM, 256, 0, stream>>>(x, fragB, out);
    } else {
        u64* wp = (u64*)d_ws;  // 16 KB
        pack_w_bits<<<4, 256, 0, stream>>>(w, wp);
        bdense_pop<<<batch / 32, 256, 0, stream>>>((const float4*)x, wp, (float4*)out);
    }
}